// Round 1
// baseline (433.043 us; speedup 1.0000x reference)
//
#include <hip/hip_runtime.h>
#include <hip/hip_bf16.h>

// NodeModel: fused GNN block on MI355X.
// Decomposition (see round-0 notes):
//   y   = x @ W1a[0:128] + b1a                     (node-level, 40k x 128)
//   r1  = relu(y[row[e]] + ea[e] @ W1a[128:192])   (edge-level, MFMA, scatter-add)
//   mean= sum(r1 by col)/max(cnt,1)
//   h1  = relu(x @ W2a[0:128] + mean @ (W1b@W2a[128:256]) + b2a
//              + [cnt>0]*(b1b@W2a[128:256]) + (u@W2a[256:320])[batch])
//   out = h1 @ W2b + b2b
// All GEMMs: bf16 MFMA 16x16x32, f32 accumulate. Threshold is 2% abs -> ok.

typedef __bf16 bf16x8 __attribute__((ext_vector_type(8)));
typedef float f32x4v __attribute__((ext_vector_type(4)));

#define NN 40000
#define NE 640000

__device__ inline bf16x8 cvt8(const float* __restrict__ p) {
  f32x4v a = *(const f32x4v*)p;
  f32x4v b = *(const f32x4v*)(p + 4);
  bf16x8 r;
  r[0] = (__bf16)a[0]; r[1] = (__bf16)a[1]; r[2] = (__bf16)a[2]; r[3] = (__bf16)a[3];
  r[4] = (__bf16)b[0]; r[5] = (__bf16)b[1]; r[6] = (__bf16)b[2]; r[7] = (__bf16)b[3];
  return r;
}

// ---------------- prep: transpose weights to bf16 B^T tables + small folds ----
// WT layout: WT[n][k] (so a lane reads 8 consecutive k as one 16B load).
__global__ __launch_bounds__(256) void prep(
    const float* __restrict__ W1a,  // 192x128
    const float* __restrict__ W2a,  // 320x128
    const float* __restrict__ W2b,  // 128x128
    const float* __restrict__ W1b,  // 128x128
    const float* __restrict__ b1b,  // 128
    const float* __restrict__ u,    // 64x64
    __bf16* __restrict__ WT1a,      // 128x192
    __bf16* __restrict__ WT2c,      // 128x128  (W2a rows 0..127)
    __bf16* __restrict__ WT2bT,     // 128x128
    __bf16* __restrict__ WT2d,      // 128x128  ((W1b @ W2a[128:256])^T)
    float* __restrict__ vtab,       // 64x128   (u @ W2a[256:320])
    float* __restrict__ bc)         // 128      (b1b @ W2a[128:256])
{
  int b = blockIdx.x, t = threadIdx.x;
  if (b < 96) {                       // WT1a: 24576 elems
    int idx = b * 256 + t; int n = idx & 127; int k = idx >> 7;
    WT1a[n * 192 + k] = (__bf16)W1a[k * 128 + n];
  } else if (b < 160) {               // WT2c
    int idx = (b - 96) * 256 + t; int n = idx & 127; int k = idx >> 7;
    WT2c[n * 128 + k] = (__bf16)W2a[k * 128 + n];
  } else if (b < 224) {               // WT2bT
    int idx = (b - 160) * 256 + t; int n = idx & 127; int k = idx >> 7;
    WT2bT[n * 128 + k] = (__bf16)W2b[k * 128 + n];
  } else if (b < 256) {               // vtab: 64x128
    int idx = (b - 224) * 256 + t; int n = idx & 127; int g = idx >> 7;
    float s = 0.f;
    for (int k = 0; k < 64; ++k) s += u[g * 64 + k] * W2a[(256 + k) * 128 + n];
    vtab[g * 128 + n] = s;
  } else if (b == 256) {              // bc
    if (t < 128) {
      float s = 0.f;
      for (int j = 0; j < 128; ++j) s += b1b[j] * W2a[(128 + j) * 128 + t];
      bc[t] = s;
    }
  } else {                            // WT2d: block 257+k, thread n
    int k = b - 257;
    if (t < 128) {
      float s = 0.f;
      for (int j = 0; j < 128; ++j) s += W1b[k * 128 + j] * W2a[(128 + j) * 128 + t];
      WT2d[t * 128 + k] = (__bf16)s;
    }
  }
}

// ---------------- edge degree (counts as float; values are small ints) -------
__global__ __launch_bounds__(256) void cnt_kernel(const int* __restrict__ EI,
                                                  float* __restrict__ cnt) {
  int e = blockIdx.x * 256 + threadIdx.x;   // grid exactly covers NE
  unsafeAtomicAdd(&cnt[EI[NE + e]], 1.0f);
}

// ---------------- fused edge GEMM + gather(y) + relu + scatter-add ----------
// wave = 16 edges x 128 cols; block = 4 waves = 64 edges. 640000/64 = 10000 blocks.
__global__ __launch_bounds__(256) void edge_kernel(
    const float* __restrict__ EA,   // 640000x64
    const int* __restrict__ EI,     // [2][640000]
    const __bf16* __restrict__ WT1a,// 128x192 (we use k=128..191)
    const float* __restrict__ Y,    // 40000x128
    float* __restrict__ SUMS)       // 40000x128
{
  int lane = threadIdx.x & 63;
  int wave = threadIdx.x >> 6;
  int eb = blockIdx.x * 64 + wave * 16;
  int g = lane >> 4, c = lane & 15;

  f32x4v acc[8];
#pragma unroll
  for (int nt = 0; nt < 8; ++nt) acc[nt] = (f32x4v)(0.f);

  const float* arow = EA + (size_t)(eb + c) * 64;
#pragma unroll
  for (int kk = 0; kk < 64; kk += 32) {
    bf16x8 af = cvt8(arow + kk + g * 8);
#pragma unroll
    for (int nt = 0; nt < 8; ++nt) {
      bf16x8 bf = *(const bf16x8*)(WT1a + (nt * 16 + c) * 192 + 128 + kk + g * 8);
      acc[nt] = __builtin_amdgcn_mfma_f32_16x16x32_bf16(af, bf, acc[nt], 0, 0, 0);
    }
  }

#pragma unroll
  for (int q = 0; q < 4; ++q) {
    int e = eb + g * 4 + q;
    int rw = EI[e];
    int cl = EI[NE + e];
    const float* yr = Y + (size_t)rw * 128;
    float* sr = SUMS + (size_t)cl * 128;
#pragma unroll
    for (int nt = 0; nt < 8; ++nt) {
      int n = nt * 16 + c;
      float v = fmaxf(acc[nt][q] + yr[n], 0.f);
      unsafeAtomicAdd(sr + n, v);
    }
  }
}

// ---------------- mean = sums / max(cnt,1) ----------------------------------
__global__ __launch_bounds__(256) void mean_kernel(const float* __restrict__ sums,
                                                   const float* __restrict__ cnt,
                                                   float* __restrict__ mean) {
  int t = blockIdx.x * 256 + threadIdx.x;  // f32x4 index; grid covers 1.28M
  f32x4v s = ((const f32x4v*)sums)[t];
  float inv = 1.f / fmaxf(cnt[t >> 5], 1.f);
  ((f32x4v*)mean)[t] = s * inv;
}

// ---------------- generic node-level GEMM (N fixed = 128) -------------------
// C[r][n] = act( A@BT1 (+ A2@BT2) + cbias[n] + [gate[r]>0]*gbias[n] + vtab[vidx[r]][n] )
__global__ __launch_bounds__(256) void mlp_gemm(
    const float* __restrict__ A, int K1, int lda1,
    const __bf16* __restrict__ BT1, int ldb1, int boff1,
    const float* __restrict__ A2, int K2, int lda2,
    const __bf16* __restrict__ BT2, int ldb2,
    const float* __restrict__ cbias,
    const float* __restrict__ gate, const float* __restrict__ gbias,
    const float* __restrict__ vtab, const int* __restrict__ vidx,
    int do_relu, float* __restrict__ C) {
  int lane = threadIdx.x & 63;
  int wave = threadIdx.x >> 6;
  int rowbase = blockIdx.x * 64 + wave * 16;
  int g = lane >> 4, c = lane & 15;

  f32x4v acc[8];
#pragma unroll
  for (int nt = 0; nt < 8; ++nt) acc[nt] = (f32x4v)(0.f);

  const float* arow = A + (size_t)(rowbase + c) * lda1;
  for (int kk = 0; kk < K1; kk += 32) {
    bf16x8 af = cvt8(arow + kk + g * 8);
#pragma unroll
    for (int nt = 0; nt < 8; ++nt) {
      bf16x8 bf = *(const bf16x8*)(BT1 + (size_t)(nt * 16 + c) * ldb1 + boff1 + kk + g * 8);
      acc[nt] = __builtin_amdgcn_mfma_f32_16x16x32_bf16(af, bf, acc[nt], 0, 0, 0);
    }
  }
  if (A2) {
    const float* arow2 = A2 + (size_t)(rowbase + c) * lda2;
    for (int kk = 0; kk < K2; kk += 32) {
      bf16x8 af = cvt8(arow2 + kk + g * 8);
#pragma unroll
      for (int nt = 0; nt < 8; ++nt) {
        bf16x8 bf = *(const bf16x8*)(BT2 + (size_t)(nt * 16 + c) * ldb2 + kk + g * 8);
        acc[nt] = __builtin_amdgcn_mfma_f32_16x16x32_bf16(af, bf, acc[nt], 0, 0, 0);
      }
    }
  }

#pragma unroll
  for (int q = 0; q < 4; ++q) {
    int r = rowbase + g * 4 + q;
    float gmul = 0.f;
    if (gbias) gmul = (gate[r] > 0.5f) ? 1.f : 0.f;
    const float* vrow = vtab ? (vtab + (size_t)vidx[r] * 128) : nullptr;
#pragma unroll
    for (int nt = 0; nt < 8; ++nt) {
      int n = nt * 16 + c;
      float v = acc[nt][q];
      if (cbias) v += cbias[n];
      if (gbias) v += gmul * gbias[n];
      if (vrow) v += vrow[n];
      if (do_relu) v = fmaxf(v, 0.f);
      C[(size_t)r * 128 + n] = v;
    }
  }
}

extern "C" void kernel_launch(void* const* d_in, const int* in_sizes, int n_in,
                              void* d_out, int out_size, void* d_ws, size_t ws_size,
                              hipStream_t stream) {
  const float* x    = (const float*)d_in[0];
  const int*   ei   = (const int*)d_in[1];
  const float* ea   = (const float*)d_in[2];
  const float* u    = (const float*)d_in[3];
  const int*   batch= (const int*)d_in[4];
  const float* W1a  = (const float*)d_in[5];
  const float* b1a  = (const float*)d_in[6];
  const float* W1b  = (const float*)d_in[7];
  const float* b1b  = (const float*)d_in[8];
  const float* W2a  = (const float*)d_in[9];
  const float* b2a  = (const float*)d_in[10];
  const float* W2b  = (const float*)d_in[11];
  const float* b2b  = (const float*)d_in[12];

  char* ws = (char*)d_ws;
  __bf16* WT1a  = (__bf16*)(ws);                 // 49152 B
  __bf16* WT2c  = (__bf16*)(ws + 49152);         // 32768
  __bf16* WT2bT = (__bf16*)(ws + 81920);         // 32768
  __bf16* WT2d  = (__bf16*)(ws + 114688);        // 32768
  float*  vtab  = (float*)(ws + 147456);         // 32768
  float*  bc    = (float*)(ws + 180224);         // 512
  float*  sums  = (float*)(ws + 180736);         // 20,480,000
  float*  cnt   = (float*)(ws + 20660736);       // 160,000
  float*  ybuf  = (float*)(ws + 20820736);       // 20,480,000 (y, then mean)
  float*  h1    = sums;                          // reuse sums after mean

  // zero the atomic accumulators (sums + cnt are contiguous)
  hipMemsetAsync(ws + 180736, 0, 20480000 + 160000, stream);

  prep<<<385, 256, 0, stream>>>(W1a, W2a, W2b, W1b, b1b, u,
                                WT1a, WT2c, WT2bT, WT2d, vtab, bc);

  // y = x @ W1a_top + b1a
  mlp_gemm<<<625, 256, 0, stream>>>(x, 128, 128, WT1a, 192, 0,
                                    nullptr, 0, 0, nullptr, 0,
                                    b1a, nullptr, nullptr, nullptr, nullptr,
                                    0, ybuf);

  cnt_kernel<<<2500, 256, 0, stream>>>(ei, cnt);

  edge_kernel<<<10000, 256, 0, stream>>>(ea, ei, WT1a, ybuf, sums);

  mean_kernel<<<5000, 256, 0, stream>>>(sums, cnt, ybuf);

  // h1 = relu(x@W2c + mean@W2d + b2a + [cnt>0]*bc + vtab[batch])
  mlp_gemm<<<625, 256, 0, stream>>>(x, 128, 128, WT2c, 128, 0,
                                    ybuf, 128, 128, WT2d, 128,
                                    b2a, cnt, bc, vtab, batch,
                                    1, h1);

  // out = h1 @ W2b + b2b
  mlp_gemm<<<625, 256, 0, stream>>>(h1, 128, 128, WT2bT, 128, 0,
                                    nullptr, 0, 0, nullptr, 0,
                                    b2b, nullptr, nullptr, nullptr, nullptr,
                                    0, (float*)d_out);
}

// Round 2
// 409.566 us; speedup vs baseline: 1.0573x; 1.0573x over previous
//
#include <hip/hip_runtime.h>
#include <hip/hip_bf16.h>

// NodeModel fused GNN block, round 2: counting-sort edges by destination,
// segmented reduction in LDS -> ~12x fewer atomics, coalesced Y gathers.
//   y    = x @ W1a[0:128] + b1a                  (bf16, 40k x 128)
//   t_e  = ea[e] @ W1a[128:192]                  (MFMA, raw acc -> LDS)
//   sums = segmented-sum over sorted e of relu(y[row_e] + t_e)
//   mean = sums / max(cnt,1)                     (bf16)
//   h1   = relu(x@W2c + mean@(W1b@W2a_mid) + b2a + [cnt>0]*bc + (u@W2a_u)[batch])
//   out  = h1 @ W2b + b2b

typedef __bf16 bf16x8 __attribute__((ext_vector_type(8)));
typedef float f32x4v __attribute__((ext_vector_type(4)));

#define NN 40000
#define NE 640000

__device__ inline bf16x8 cvt8(const float* __restrict__ p) {
  f32x4v a = *(const f32x4v*)p;
  f32x4v b = *(const f32x4v*)(p + 4);
  bf16x8 r;
  r[0] = (__bf16)a[0]; r[1] = (__bf16)a[1]; r[2] = (__bf16)a[2]; r[3] = (__bf16)a[3];
  r[4] = (__bf16)b[0]; r[5] = (__bf16)b[1]; r[6] = (__bf16)b[2]; r[7] = (__bf16)b[3];
  return r;
}

// ---------------- prep: bf16 B^T weight tables + small folds ----------------
__global__ __launch_bounds__(256) void prep(
    const float* __restrict__ W1a, const float* __restrict__ W2a,
    const float* __restrict__ W2b, const float* __restrict__ W1b,
    const float* __restrict__ b1b, const float* __restrict__ u,
    __bf16* __restrict__ WT1a,   // 128x192
    __bf16* __restrict__ WT2c,   // 128x128
    __bf16* __restrict__ WT2bT,  // 128x128
    __bf16* __restrict__ WT2d,   // 128x128
    float* __restrict__ vtab,    // 64x128
    float* __restrict__ bc)      // 128
{
  int b = blockIdx.x, t = threadIdx.x;
  if (b < 96) {
    int idx = b * 256 + t; int n = idx & 127; int k = idx >> 7;
    WT1a[n * 192 + k] = (__bf16)W1a[k * 128 + n];
  } else if (b < 160) {
    int idx = (b - 96) * 256 + t; int n = idx & 127; int k = idx >> 7;
    WT2c[n * 128 + k] = (__bf16)W2a[k * 128 + n];
  } else if (b < 224) {
    int idx = (b - 160) * 256 + t; int n = idx & 127; int k = idx >> 7;
    WT2bT[n * 128 + k] = (__bf16)W2b[k * 128 + n];
  } else if (b < 256) {
    int idx = (b - 224) * 256 + t; int n = idx & 127; int g = idx >> 7;
    float s = 0.f;
    for (int k = 0; k < 64; ++k) s += u[g * 64 + k] * W2a[(256 + k) * 128 + n];
    vtab[g * 128 + n] = s;
  } else if (b == 256) {
    if (t < 128) {
      float s = 0.f;
      for (int j = 0; j < 128; ++j) s += b1b[j] * W2a[(128 + j) * 128 + t];
      bc[t] = s;
    }
  } else {
    int k = b - 257;
    if (t < 128) {
      float s = 0.f;
      for (int j = 0; j < 128; ++j) s += W1b[k * 128 + j] * W2a[(128 + j) * 128 + t];
      WT2d[t * 128 + k] = (__bf16)s;
    }
  }
}

// ---------------- counting sort by destination ------------------------------
__global__ __launch_bounds__(256) void hist_kernel(const int* __restrict__ EI,
                                                   int* __restrict__ cnt) {
  int e = blockIdx.x * 256 + threadIdx.x;   // grid exactly covers NE
  atomicAdd(&cnt[EI[NE + e]], 1);
}

__global__ __launch_bounds__(1024) void scan_kernel(const int* __restrict__ cnt,
                                                    int* __restrict__ offsets) {
  __shared__ int part[1024];
  int t = threadIdx.x;
  int base = t * 40;
  int s = 0;
  for (int k = 0; k < 40; ++k) {
    int idx = base + k;
    if (idx < NN) s += cnt[idx];
  }
  part[t] = s;
  __syncthreads();
  for (int off = 1; off < 1024; off <<= 1) {
    int v = (t >= off) ? part[t - off] : 0;
    __syncthreads();
    part[t] += v;
    __syncthreads();
  }
  int pre = part[t] - s;   // exclusive prefix of this thread's chunk
  for (int k = 0; k < 40; ++k) {
    int idx = base + k;
    if (idx < NN) { offsets[idx] = pre; pre += cnt[idx]; }
  }
}

__global__ __launch_bounds__(256) void scatter_kernel(const int* __restrict__ EI,
                                                      int* __restrict__ offsets,
                                                      int* __restrict__ se,
                                                      unsigned int* __restrict__ srowcol) {
  int e = blockIdx.x * 256 + threadIdx.x;
  int col = EI[NE + e];
  int row = EI[e];
  int pos = atomicAdd(&offsets[col], 1);
  se[pos] = e;
  srowcol[pos] = ((unsigned)row << 16) | (unsigned)col;
}

// ---------------- fused edge GEMM + segmented scatter-reduce ----------------
// block = 256 thr = 4 waves x 16 edges = 64 sorted edges. 10000 blocks.
__global__ __launch_bounds__(256) void edge_kernel(
    const float* __restrict__ EA,        // 640000x64
    const int* __restrict__ se,          // sorted edge ids
    const unsigned int* __restrict__ srowcol,
    const __bf16* __restrict__ WT1a,     // 128x192, use k=128..191
    const __bf16* __restrict__ Yb,       // 40000x128 bf16
    float* __restrict__ SUMS)            // 40000x128 f32, zeroed
{
  __shared__ float vbuf[64 * 132];
  __shared__ int ledge[64], lrow[64], lcol[64];
  int t = threadIdx.x;
  int i0 = blockIdx.x * 64;
  if (t < 64) {
    ledge[t] = se[i0 + t];
    unsigned rc = srowcol[i0 + t];
    lrow[t] = (int)(rc >> 16);
    lcol[t] = (int)(rc & 0xffffu);
  }
  __syncthreads();

  int lane = t & 63, w = t >> 6, g = lane >> 4, c = lane & 15;
  f32x4v acc[8];
#pragma unroll
  for (int nt = 0; nt < 8; ++nt) acc[nt] = (f32x4v)(0.f);

  const float* arow = EA + (size_t)ledge[w * 16 + c] * 64;
#pragma unroll
  for (int kk = 0; kk < 64; kk += 32) {
    bf16x8 af = cvt8(arow + kk + g * 8);
#pragma unroll
    for (int nt = 0; nt < 8; ++nt) {
      bf16x8 bf = *(const bf16x8*)(WT1a + (nt * 16 + c) * 192 + 128 + kk + g * 8);
      acc[nt] = __builtin_amdgcn_mfma_f32_16x16x32_bf16(af, bf, acc[nt], 0, 0, 0);
    }
  }
#pragma unroll
  for (int q = 0; q < 4; ++q) {
    int r = w * 16 + g * 4 + q;
#pragma unroll
    for (int nt = 0; nt < 8; ++nt)
      vbuf[r * 132 + nt * 16 + c] = acc[nt][q];
  }
  __syncthreads();

  // segmented reduce: thread = (half h, column n); rows sorted by col.
  int h = t >> 7, n = t & 127;
  int rbase = h * 32;
  float sum = 0.f;
  int cur = lcol[rbase];
#pragma unroll 8
  for (int r = rbase; r < rbase + 32; ++r) {
    int col = lcol[r];
    float yv = (float)Yb[(size_t)lrow[r] * 128 + n];
    float v = fmaxf(vbuf[r * 132 + n] + yv, 0.f);
    if (col != cur) {
      unsafeAtomicAdd(&SUMS[(size_t)cur * 128 + n], sum);
      sum = 0.f; cur = col;
    }
    sum += v;
  }
  unsafeAtomicAdd(&SUMS[(size_t)cur * 128 + n], sum);
}

// ---------------- mean = sums / max(cnt,1), store bf16 ----------------------
typedef unsigned short u16x4 __attribute__((ext_vector_type(4)));
__global__ __launch_bounds__(256) void mean_kernel(const float* __restrict__ sums,
                                                   const int* __restrict__ cnt,
                                                   __bf16* __restrict__ meanb) {
  int t4 = blockIdx.x * 256 + threadIdx.x;   // grid covers 1.28M f32x4 groups
  f32x4v s = ((const f32x4v*)sums)[t4];
  float inv = 1.f / fmaxf((float)cnt[t4 >> 5], 1.f);
  __bf16 o0 = (__bf16)(s[0] * inv), o1 = (__bf16)(s[1] * inv);
  __bf16 o2 = (__bf16)(s[2] * inv), o3 = (__bf16)(s[3] * inv);
  u16x4 pk;
  pk[0] = __builtin_bit_cast(unsigned short, o0);
  pk[1] = __builtin_bit_cast(unsigned short, o1);
  pk[2] = __builtin_bit_cast(unsigned short, o2);
  pk[3] = __builtin_bit_cast(unsigned short, o3);
  ((u16x4*)meanb)[t4] = pk;
}

// ---------------- node-level GEMM (N=128), optional 2nd bf16 A --------------
__global__ __launch_bounds__(256) void mlp_gemm(
    const float* __restrict__ A, int K1, int lda1,
    const __bf16* __restrict__ BT1, int ldb1, int boff1,
    const __bf16* __restrict__ A2b, int K2, int lda2,
    const __bf16* __restrict__ BT2, int ldb2,
    const float* __restrict__ cbias,
    const int* __restrict__ gate, const float* __restrict__ gbias,
    const float* __restrict__ vtab, const int* __restrict__ vidx,
    int do_relu, float* __restrict__ Cf, __bf16* __restrict__ Cb) {
  int lane = threadIdx.x & 63;
  int wave = threadIdx.x >> 6;
  int rowbase = blockIdx.x * 64 + wave * 16;
  int g = lane >> 4, c = lane & 15;

  f32x4v acc[8];
#pragma unroll
  for (int nt = 0; nt < 8; ++nt) acc[nt] = (f32x4v)(0.f);

  const float* arow = A + (size_t)(rowbase + c) * lda1;
  for (int kk = 0; kk < K1; kk += 32) {
    bf16x8 af = cvt8(arow + kk + g * 8);
#pragma unroll
    for (int nt = 0; nt < 8; ++nt) {
      bf16x8 bf = *(const bf16x8*)(BT1 + (size_t)(nt * 16 + c) * ldb1 + boff1 + kk + g * 8);
      acc[nt] = __builtin_amdgcn_mfma_f32_16x16x32_bf16(af, bf, acc[nt], 0, 0, 0);
    }
  }
  if (A2b) {
    const __bf16* arow2 = A2b + (size_t)(rowbase + c) * lda2;
    for (int kk = 0; kk < K2; kk += 32) {
      bf16x8 af = *(const bf16x8*)(arow2 + kk + g * 8);
#pragma unroll
      for (int nt = 0; nt < 8; ++nt) {
        bf16x8 bf = *(const bf16x8*)(BT2 + (size_t)(nt * 16 + c) * ldb2 + kk + g * 8);
        acc[nt] = __builtin_amdgcn_mfma_f32_16x16x32_bf16(af, bf, acc[nt], 0, 0, 0);
      }
    }
  }

#pragma unroll
  for (int q = 0; q < 4; ++q) {
    int r = rowbase + g * 4 + q;
    float gmul = 0.f;
    if (gbias) gmul = gate[r] ? 1.f : 0.f;
    const float* vrow = vtab ? (vtab + (size_t)vidx[r] * 128) : nullptr;
#pragma unroll
    for (int nt = 0; nt < 8; ++nt) {
      int n = nt * 16 + c;
      float v = acc[nt][q];
      if (cbias) v += cbias[n];
      if (gbias) v += gmul * gbias[n];
      if (vrow) v += vrow[n];
      if (do_relu) v = fmaxf(v, 0.f);
      if (Cb) Cb[(size_t)r * 128 + n] = (__bf16)v;
      else    Cf[(size_t)r * 128 + n] = v;
    }
  }
}

extern "C" void kernel_launch(void* const* d_in, const int* in_sizes, int n_in,
                              void* d_out, int out_size, void* d_ws, size_t ws_size,
                              hipStream_t stream) {
  const float* x    = (const float*)d_in[0];
  const int*   ei   = (const int*)d_in[1];
  const float* ea   = (const float*)d_in[2];
  const float* u    = (const float*)d_in[3];
  const int*   batch= (const int*)d_in[4];
  const float* W1a  = (const float*)d_in[5];
  const float* b1a  = (const float*)d_in[6];
  const float* W1b  = (const float*)d_in[7];
  const float* b1b  = (const float*)d_in[8];
  const float* W2a  = (const float*)d_in[9];
  const float* b2a  = (const float*)d_in[10];
  const float* W2b  = (const float*)d_in[11];
  const float* b2b  = (const float*)d_in[12];

  char* ws = (char*)d_ws;
  __bf16* WT1a   = (__bf16*)(ws);                 // 49152
  __bf16* WT2c   = (__bf16*)(ws + 49152);         // 32768
  __bf16* WT2bT  = (__bf16*)(ws + 81920);         // 32768
  __bf16* WT2d   = (__bf16*)(ws + 114688);        // 32768
  float*  vtab   = (float*)(ws + 147456);         // 32768
  float*  bc     = (float*)(ws + 180224);         // 512
  float*  sums   = (float*)(ws + 180736);         // 20,480,000 (later: h1)
  int*    cnt    = (int*)(ws + 20660736);         // 160,000
  int*    offs   = (int*)(ws + 20820736);         // 160,000
  __bf16* ybufb  = (__bf16*)(ws + 20980736);      // 10,240,000 (y, then mean)
  int*    se     = (int*)(ws + 31220736);         // 2,560,000
  unsigned int* srowcol = (unsigned int*)(ws + 33780736); // 2,560,000
  float*  h1     = sums;

  // zero atomic accumulators (sums + cnt contiguous)
  hipMemsetAsync(ws + 180736, 0, 20480000 + 160000, stream);

  prep<<<385, 256, 0, stream>>>(W1a, W2a, W2b, W1b, b1b, u,
                                WT1a, WT2c, WT2bT, WT2d, vtab, bc);

  // y = x @ W1a_top + b1a  -> bf16
  mlp_gemm<<<625, 256, 0, stream>>>(x, 128, 128, WT1a, 192, 0,
                                    nullptr, 0, 0, nullptr, 0,
                                    b1a, nullptr, nullptr, nullptr, nullptr,
                                    0, nullptr, ybufb);

  hist_kernel<<<2500, 256, 0, stream>>>(ei, cnt);
  scan_kernel<<<1, 1024, 0, stream>>>(cnt, offs);
  scatter_kernel<<<2500, 256, 0, stream>>>(ei, offs, se, srowcol);

  edge_kernel<<<10000, 256, 0, stream>>>(ea, se, srowcol, WT1a, ybufb, sums);

  mean_kernel<<<5000, 256, 0, stream>>>(sums, cnt, ybufb);

  // h1 = relu(x@W2c + mean@W2d + b2a + [cnt>0]*bc + vtab[batch])
  mlp_gemm<<<625, 256, 0, stream>>>(x, 128, 128, WT2c, 128, 0,
                                    ybufb, 128, 128, WT2d, 128,
                                    b2a, cnt, bc, vtab, batch,
                                    1, h1, nullptr);

  // out = h1 @ W2b + b2b
  mlp_gemm<<<625, 256, 0, stream>>>(h1, 128, 128, WT2bT, 128, 0,
                                    nullptr, 0, 0, nullptr, 0,
                                    b2b, nullptr, nullptr, nullptr, nullptr,
                                    0, (float*)d_out, nullptr);
}